// Round 3
// baseline (1158.629 us; speedup 1.0000x reference)
//
#include <hip/hip_runtime.h>

#define FEAT    83
#define DIMF    64
#define LAT     32
#define THREADS 256

__global__ __launch_bounds__(THREADS, 6)
void material_encoder_kernel(const float* __restrict__ inp,
                             const float* __restrict__ shiftp,
                             const float* __restrict__ W1,
                             const float* __restrict__ b1,
                             const float* __restrict__ Wh0,
                             const float* __restrict__ bh0,
                             const float* __restrict__ Wh1,
                             const float* __restrict__ bh1,
                             float* __restrict__ out,
                             int nrows)
{
    const int row = blockIdx.x * THREADS + threadIdx.x;
    if (row >= nrows) return;

    const float sh = shiftp[0];
    const float* __restrict__ xg = inp + (long long)row * FEAT;

    // ---- layer 1: h[64] = relu((x+shift) @ W1 + b1) ----
    // i-outer / k-inner: weight reads are SEQUENTIAL (one 256B W1 row at a
    // time) -> s_load_dwordx16 streams with small SGPR live set.
    float h[DIMF];
    #pragma unroll
    for (int k = 0; k < DIMF; ++k) h[k] = b1[k];

    float nzmax = 0.0f;           // any(x!=0)  <=>  max|x| != 0
    float xa[4], xb[4];
    #pragma unroll
    for (int i = 0; i < 4; ++i) xa[i] = xg[i];

    #pragma unroll 1
    for (int jb = 0; jb < 80; jb += 4) {
        // prefetch next batch (vmcnt wait lands after the 256 FMAs below)
        if (jb < 76) {
            #pragma unroll
            for (int i = 0; i < 4; ++i) xb[i] = xg[jb + 4 + i];
        } else {            // prefetch the 3-elem tail; never touch xg[83] (OOB)
            xb[0] = xg[80]; xb[1] = xg[81]; xb[2] = xg[82]; xb[3] = 0.0f;
        }
        #pragma unroll
        for (int i = 0; i < 4; ++i) {
            nzmax = fmaxf(nzmax, fabsf(xa[i]));
            const float xs = xa[i] + sh;
            const float* __restrict__ w = W1 + (jb + i) * DIMF;  // uniform -> s_load
            #pragma unroll
            for (int k = 0; k < DIMF; ++k)
                h[k] = fmaf(xs, w[k], h[k]);
        }
        #pragma unroll
        for (int i = 0; i < 4; ++i) xa[i] = xb[i];
    }
    // tail rows 80..82 (sitting in xa[0..2])
    #pragma unroll
    for (int i = 0; i < 3; ++i) {
        nzmax = fmaxf(nzmax, fabsf(xa[i]));
        const float xs = xa[i] + sh;
        const float* __restrict__ w = W1 + (80 + i) * DIMF;
        #pragma unroll
        for (int k = 0; k < DIMF; ++k)
            h[k] = fmaf(xs, w[k], h[k]);
    }
    #pragma unroll
    for (int k = 0; k < DIMF; ++k) h[k] = fmaxf(h[k], 0.0f);

    // ---- layer 2: g[32] = relu(h @ Wh0 + bh0); Wh0 row-major, k-outer ->
    // sequential s_load stream ----
    float g[LAT];
    #pragma unroll
    for (int m = 0; m < LAT; ++m) g[m] = bh0[m];
    #pragma unroll
    for (int k = 0; k < DIMF; ++k) {
        #pragma unroll
        for (int m = 0; m < LAT; ++m)
            g[m] = fmaf(h[k], Wh0[k * LAT + m], g[m]);
    }
    #pragma unroll
    for (int m = 0; m < LAT; ++m) g[m] = fmaxf(g[m], 0.0f);

    // ---- layer 3: e[32] = relu(g @ Wh1 + bh1) ----
    float e[LAT];
    #pragma unroll
    for (int m = 0; m < LAT; ++m) e[m] = bh1[m];
    #pragma unroll
    for (int q = 0; q < LAT; ++q) {
        #pragma unroll
        for (int m = 0; m < LAT; ++m)
            e[m] = fmaf(g[q], Wh1[q * LAT + m], e[m]);
    }

    // ---- relu + L2 normalize + mask ----
    float ss = 0.0f;
    #pragma unroll
    for (int m = 0; m < LAT; ++m) {
        e[m] = fmaxf(e[m], 0.0f);
        ss = fmaf(e[m], e[m], ss);
    }
    const float scale = (nzmax != 0.0f) ? (1.0f / fmaxf(sqrtf(ss), 1e-12f)) : 0.0f;

    // ---- write 3 identical copies, float4 per thread ----
    float4 v[8];
    #pragma unroll
    for (int q = 0; q < 8; ++q) {
        v[q].x = e[q * 4 + 0] * scale;
        v[q].y = e[q * 4 + 1] * scale;
        v[q].z = e[q * 4 + 2] * scale;
        v[q].w = e[q * 4 + 3] * scale;
    }
    const long long obase = (long long)row * LAT;
    const long long osz   = (long long)nrows * LAT;
    float4* o0 = (float4*)(out + obase);
    float4* o1 = (float4*)(out + osz + obase);
    float4* o2 = (float4*)(out + 2 * osz + obase);
    #pragma unroll
    for (int q = 0; q < 8; ++q) o0[q] = v[q];
    #pragma unroll
    for (int q = 0; q < 8; ++q) o1[q] = v[q];
    #pragma unroll
    for (int q = 0; q < 8; ++q) o2[q] = v[q];
}

extern "C" void kernel_launch(void* const* d_in, const int* in_sizes, int n_in,
                              void* d_out, int out_size, void* d_ws, size_t ws_size,
                              hipStream_t stream) {
    const float* inp    = (const float*)d_in[0];
    const float* shiftp = (const float*)d_in[1];
    const float* W1     = (const float*)d_in[2];
    const float* b1     = (const float*)d_in[3];
    const float* Wh0    = (const float*)d_in[4];
    const float* bh0    = (const float*)d_in[5];
    const float* Wh1    = (const float*)d_in[6];
    const float* bh1    = (const float*)d_in[7];
    float* out = (float*)d_out;

    const int nrows = in_sizes[0] / FEAT;               // 2,000,000
    const int blocks = (nrows + THREADS - 1) / THREADS; // 7813

    material_encoder_kernel<<<dim3(blocks), dim3(THREADS), 0, stream>>>(
        inp, shiftp, W1, b1, Wh0, bh0, Wh1, bh1, out, nrows);
}

// Round 5
// 330.992 us; speedup vs baseline: 3.5005x; 3.5005x over previous
//
#include <hip/hip_runtime.h>

#define FEAT 83
#define DIMF 64
#define LAT  32
#define THREADS 256
#define RPB  128            // rows per block: 4 waves x 32 rows

typedef __attribute__((ext_vector_type(8))) short bf16x8;
typedef __attribute__((ext_vector_type(4))) float f32x4;

// LDS strides in bf16 elements (all rows 16B-aligned, <=2-way bank aliasing)
#define BT1_S 104           // W1^T  [64][104], K padded to 96, pad zeroed
#define BT2_S 72            // Wh0^T [32][72],  K=64
#define BT3_S 40            // Wh1^T [32][40],  K=32
#define HT_S  72            // per-wave h tile [32][72]
#define GT_S  40            // per-wave g tile [32][40]

// region map (shorts):
//  A region: phase1 = bt1_hi(6656)+bt1_lo(6656)=13312; phase2 = 4 waves x 4608
//            per-wave scratch (ht_hi 2304 + ht_lo 2304; later gt_hi/gt_lo
//            overlay the same scratch after layer-2 reads -- same-wave order)
#define A_OFF   0
#define BT1LO   6656
#define WSCR    4608        // per-wave scratch shorts
#define B_OFF   18432       // bt2_hi
#define BT2LO   (B_OFF + 2304)
#define C_OFF   23040       // bt3_hi
#define BT3LO   (C_OFF + 1280)
#define M_OFF   25600       // 128 floats of row-mask (byte 51200, 16B aligned)
#define SM_TOT  25856       // 51712 bytes -> 3 blocks/CU

__device__ __forceinline__ short f2b(float f) {   // fp32 -> bf16 RNE
    unsigned u = __float_as_uint(f);
    u += 0x7fffu + ((u >> 16) & 1u);
    return (short)(u >> 16);
}
__device__ __forceinline__ float b2f(short h) {   // bf16 -> fp32 exact
    return __uint_as_float(((unsigned)(unsigned short)h) << 16);
}

__global__ __launch_bounds__(THREADS, 3)
void material_encoder_kernel(const float* __restrict__ inp,
                             const float* __restrict__ shiftp,
                             const float* __restrict__ W1,
                             const float* __restrict__ b1,
                             const float* __restrict__ Wh0,
                             const float* __restrict__ bh0,
                             const float* __restrict__ Wh1,
                             const float* __restrict__ bh1,
                             float* __restrict__ out,
                             int nrows)
{
    __shared__ __align__(16) short sm[SM_TOT];
    float* maskf = (float*)(sm + M_OFF);

    const int t    = threadIdx.x;
    const int lane = t & 63;
    const int wv   = t >> 6;
    const int lr   = lane & 15;        // A-row / B-col / C-col index
    const int lq   = (lane >> 4) & 3;  // lane quarter

    // ---- stage weights to LDS as bf16 hi/lo B^T tiles ----
    for (int f = t; f < FEAT * DIMF; f += THREADS) {      // W1: 83x64
        int j = f >> 6, c = f & 63;
        float w = W1[f];
        short hi = f2b(w);
        sm[A_OFF + c * BT1_S + j] = hi;
        sm[BT1LO + c * BT1_S + j] = f2b(w - b2f(hi));
    }
    if (t < DIMF) {                                       // zero K-pad 83..95
        #pragma unroll
        for (int k = FEAT; k < 96; ++k) {
            sm[A_OFF + t * BT1_S + k] = 0;
            sm[BT1LO + t * BT1_S + k] = 0;
        }
    }
    for (int f = t; f < DIMF * LAT; f += THREADS) {       // Wh0: 64x32
        int j = f >> 5, c = f & 31;
        float w = Wh0[f];
        short hi = f2b(w);
        sm[B_OFF + c * BT2_S + j] = hi;
        sm[BT2LO + c * BT2_S + j] = f2b(w - b2f(hi));
    }
    for (int f = t; f < LAT * LAT; f += THREADS) {        // Wh1: 32x32
        int j = f >> 5, c = f & 31;
        float w = Wh1[f];
        short hi = f2b(w);
        sm[C_OFF + c * BT3_S + j] = hi;
        sm[BT3LO + c * BT3_S + j] = f2b(w - b2f(hi));
    }

    // biases per lane (L1/L2 cached)
    float bias1[4], bias2[2], bias3[2];
    #pragma unroll
    for (int n = 0; n < 4; ++n) bias1[n] = b1[lr + 16 * n];
    #pragma unroll
    for (int n = 0; n < 2; ++n) { bias2[n] = bh0[lr + 16 * n]; bias3[n] = bh1[lr + 16 * n]; }

    const float sh = shiftp[0];
    const int Rw = blockIdx.x * RPB + wv * 32;

    // ---- A fragments (x+shift) hi/lo straight from global; nz mask on raw x ----
    // frag layout (16x16x32): row = lr, k = 8*lq + i (+32*s)
    bf16x8 a1h[2][3], a1l[2][3];
    float nzm[2];
    #pragma unroll
    for (int m = 0; m < 2; ++m) {
        const float* __restrict__ xr = inp + (long long)(Rw + 16 * m + lr) * FEAT;
        float nz = 0.f;
        #pragma unroll
        for (int s = 0; s < 3; ++s) {
            const int k0 = 32 * s + 8 * lq;
            float v[8];
            #pragma unroll
            for (int i = 0; i < 8; ++i) {
                float x = 0.f;
                if (k0 + i < FEAT) x = xr[k0 + i];   // predicated; pads -> 0
                v[i] = x;
            }
            bf16x8 fh, fl;
            #pragma unroll
            for (int i = 0; i < 8; ++i) {
                nz = fmaxf(nz, fabsf(v[i]));
                const float xs = v[i] + sh;          // pad lanes hit zeroed B-pad
                short hi = f2b(xs);
                fh[i] = hi;
                fl[i] = f2b(xs - b2f(hi));
            }
            a1h[m][s] = fh;
            a1l[m][s] = fl;
        }
        nzm[m] = nz;
    }
    #pragma unroll
    for (int m = 0; m < 2; ++m) {     // full-row max across the 4 k-quarters
        nzm[m] = fmaxf(nzm[m], __shfl_xor(nzm[m], 16));
        nzm[m] = fmaxf(nzm[m], __shfl_xor(nzm[m], 32));
    }
    if (lq == 0) {
        maskf[wv * 32 + lr]      = nzm[0];
        maskf[wv * 32 + 16 + lr] = nzm[1];
    }

    __syncthreads();   // weights staged

    // ---- layer 1: 2(M) x 4(N) x 3(K) x 3 split-terms ----
    f32x4 acc[2][4];
    #pragma unroll
    for (int m = 0; m < 2; ++m)
        #pragma unroll
        for (int n = 0; n < 4; ++n)
            acc[m][n] = (f32x4){bias1[n], bias1[n], bias1[n], bias1[n]};

    #pragma unroll
    for (int s = 0; s < 3; ++s)
        #pragma unroll
        for (int n = 0; n < 4; ++n) {
            bf16x8 bh = *(const bf16x8*)&sm[A_OFF + (lr + 16 * n) * BT1_S + 32 * s + 8 * lq];
            bf16x8 bl = *(const bf16x8*)&sm[BT1LO + (lr + 16 * n) * BT1_S + 32 * s + 8 * lq];
            #pragma unroll
            for (int m = 0; m < 2; ++m) {
                acc[m][n] = __builtin_amdgcn_mfma_f32_16x16x32_bf16(a1h[m][s], bh, acc[m][n], 0, 0, 0);
                acc[m][n] = __builtin_amdgcn_mfma_f32_16x16x32_bf16(a1l[m][s], bh, acc[m][n], 0, 0, 0);
                acc[m][n] = __builtin_amdgcn_mfma_f32_16x16x32_bf16(a1h[m][s], bl, acc[m][n], 0, 0, 0);
            }
        }

    __syncthreads();   // all waves done reading bt1 -> region A = per-wave scratch

    // ---- h: relu -> hi/lo bf16 -> per-wave LDS transpose (C-layout -> A-layout) ----
    short* ht_hi = sm + A_OFF + wv * WSCR;
    short* ht_lo = ht_hi + 2304;
    #pragma unroll
    for (int m = 0; m < 2; ++m)
        #pragma unroll
        for (int n = 0; n < 4; ++n)
            #pragma unroll
            for (int r = 0; r < 4; ++r) {
                float hv = fmaxf(acc[m][n][r], 0.f);
                short hi = f2b(hv);
                const int idx = (16 * m + 4 * lq + r) * HT_S + lr + 16 * n;
                ht_hi[idx] = hi;
                ht_lo[idx] = f2b(hv - b2f(hi));
            }

    // ---- layer 2: 2 x 2 x 2 x 3 terms (same-wave ds_write->ds_read, no barrier) ----
    f32x4 acc2[2][2];
    #pragma unroll
    for (int m = 0; m < 2; ++m)
        #pragma unroll
        for (int n = 0; n < 2; ++n)
            acc2[m][n] = (f32x4){bias2[n], bias2[n], bias2[n], bias2[n]};

    #pragma unroll
    for (int s = 0; s < 2; ++s) {
        bf16x8 a2h[2], a2l[2];
        #pragma unroll
        for (int m = 0; m < 2; ++m) {
            const int idx = (lr + 16 * m) * HT_S + 32 * s + 8 * lq;
            a2h[m] = *(const bf16x8*)&ht_hi[idx];
            a2l[m] = *(const bf16x8*)&ht_lo[idx];
        }
        #pragma unroll
        for (int n = 0; n < 2; ++n) {
            bf16x8 bh = *(const bf16x8*)&sm[B_OFF + (lr + 16 * n) * BT2_S + 32 * s + 8 * lq];
            bf16x8 bl = *(const bf16x8*)&sm[BT2LO + (lr + 16 * n) * BT2_S + 32 * s + 8 * lq];
            #pragma unroll
            for (int m = 0; m < 2; ++m) {
                acc2[m][n] = __builtin_amdgcn_mfma_f32_16x16x32_bf16(a2h[m], bh, acc2[m][n], 0, 0, 0);
                acc2[m][n] = __builtin_amdgcn_mfma_f32_16x16x32_bf16(a2l[m], bh, acc2[m][n], 0, 0, 0);
                acc2[m][n] = __builtin_amdgcn_mfma_f32_16x16x32_bf16(a2h[m], bl, acc2[m][n], 0, 0, 0);
            }
        }
    }

    // ---- g: relu -> hi/lo -> overlay own (dead) ht scratch; same-wave order ----
    short* gt_hi = sm + A_OFF + wv * WSCR;
    short* gt_lo = gt_hi + 1280;
    #pragma unroll
    for (int m = 0; m < 2; ++m)
        #pragma unroll
        for (int n = 0; n < 2; ++n)
            #pragma unroll
            for (int r = 0; r < 4; ++r) {
                float gv = fmaxf(acc2[m][n][r], 0.f);
                short hi = f2b(gv);
                const int idx = (16 * m + 4 * lq + r) * GT_S + lr + 16 * n;
                gt_hi[idx] = hi;
                gt_lo[idx] = f2b(gv - b2f(hi));
            }

    // ---- layer 3: 2 x 2 x 1 x 3 terms ----
    f32x4 acc3[2][2];
    #pragma unroll
    for (int m = 0; m < 2; ++m)
        #pragma unroll
        for (int n = 0; n < 2; ++n)
            acc3[m][n] = (f32x4){bias3[n], bias3[n], bias3[n], bias3[n]};

    {
        bf16x8 a3h[2], a3l[2];
        #pragma unroll
        for (int m = 0; m < 2; ++m) {
            const int idx = (lr + 16 * m) * GT_S + 8 * lq;
            a3h[m] = *(const bf16x8*)&gt_hi[idx];
            a3l[m] = *(const bf16x8*)&gt_lo[idx];
        }
        #pragma unroll
        for (int n = 0; n < 2; ++n) {
            bf16x8 bh = *(const bf16x8*)&sm[C_OFF + (lr + 16 * n) * BT3_S + 8 * lq];
            bf16x8 bl = *(const bf16x8*)&sm[BT3LO + (lr + 16 * n) * BT3_S + 8 * lq];
            #pragma unroll
            for (int m = 0; m < 2; ++m) {
                acc3[m][n] = __builtin_amdgcn_mfma_f32_16x16x32_bf16(a3h[m], bh, acc3[m][n], 0, 0, 0);
                acc3[m][n] = __builtin_amdgcn_mfma_f32_16x16x32_bf16(a3l[m], bh, acc3[m][n], 0, 0, 0);
                acc3[m][n] = __builtin_amdgcn_mfma_f32_16x16x32_bf16(a3h[m], bl, acc3[m][n], 0, 0, 0);
            }
        }
    }

    // ---- relu + row L2 norm (reduce over cols = over lr lanes) + mask ----
    float er[2][2][4];
    float ssq[2][4];
    #pragma unroll
    for (int m = 0; m < 2; ++m)
        #pragma unroll
        for (int r = 0; r < 4; ++r) ssq[m][r] = 0.f;
    #pragma unroll
    for (int m = 0; m < 2; ++m)
        #pragma unroll
        for (int n = 0; n < 2; ++n)
            #pragma unroll
            for (int r = 0; r < 4; ++r) {
                float e = fmaxf(acc3[m][n][r], 0.f);
                er[m][n][r] = e;
                ssq[m][r] = fmaf(e, e, ssq[m][r]);
            }
    #pragma unroll
    for (int msk = 1; msk <= 8; msk <<= 1)
        #pragma unroll
        for (int m = 0; m < 2; ++m)
            #pragma unroll
            for (int r = 0; r < 4; ++r)
                ssq[m][r] += __shfl_xor(ssq[m][r], msk);

    const float* maskp = maskf + wv * 32;
    f32x4 mk[2];
    mk[0] = *(const f32x4*)&maskp[4 * lq];
    mk[1] = *(const f32x4*)&maskp[16 + 4 * lq];

    float sc[2][4];
    #pragma unroll
    for (int m = 0; m < 2; ++m)
        #pragma unroll
        for (int r = 0; r < 4; ++r)
            // rsqrt(max(ss,1e-24)) == 1/max(sqrt(ss),1e-12)
            sc[m][r] = (mk[m][r] != 0.f) ? rsqrtf(fmaxf(ssq[m][r], 1e-24f)) : 0.f;

    // ---- store 3 copies (quarter-wave 64B segments) ----
    const int osz = nrows * LAT;                 // 64M, fits int
    float* __restrict__ ob = out + (long long)Rw * LAT;
    #pragma unroll
    for (int m = 0; m < 2; ++m)
        #pragma unroll
        for (int r = 0; r < 4; ++r) {
            const int ro = (16 * m + 4 * lq + r) * LAT;
            #pragma unroll
            for (int n = 0; n < 2; ++n) {
                const float vv = er[m][n][r] * sc[m][r];
                const int cc = ro + lr + 16 * n;
                ob[cc]           = vv;
                ob[osz + cc]     = vv;
                ob[2 * osz + cc] = vv;
            }
        }
}

extern "C" void kernel_launch(void* const* d_in, const int* in_sizes, int n_in,
                              void* d_out, int out_size, void* d_ws, size_t ws_size,
                              hipStream_t stream) {
    const float* inp    = (const float*)d_in[0];
    const float* shiftp = (const float*)d_in[1];
    const float* W1     = (const float*)d_in[2];
    const float* b1     = (const float*)d_in[3];
    const float* Wh0    = (const float*)d_in[4];
    const float* bh0    = (const float*)d_in[5];
    const float* Wh1    = (const float*)d_in[6];
    const float* bh1    = (const float*)d_in[7];
    float* out = (float*)d_out;

    const int nrows = in_sizes[0] / FEAT;      // 2,000,000 = 128 * 15625
    const int blocks = nrows / RPB;            // exact

    material_encoder_kernel<<<dim3(blocks), dim3(THREADS), 0, stream>>>(
        inp, shiftp, W1, b1, Wh0, bh0, Wh1, bh1, out, nrows);
}